// Round 3
// baseline (67.996 us; speedup 1.0000x reference)
//
#include <hip/hip_runtime.h>

// Problem constants (match reference)
#define NB 16      // BATCH
#define NC 32      // IN_CH
#define NO 32      // OUT_CH
#define NM 1024    // NODES
#define SEGS 32
#define WLEN 97    // (N-1)*SEGMENTS + 1

// round-to-nearest-even fp32 -> bf16 (as uint16 in low bits)
__device__ __forceinline__ unsigned f2bf(float f) {
    unsigned u = __float_as_uint(f);
    return (u + 0x7fffu + ((u >> 16) & 1u)) >> 16;
}

// ---------------------------------------------------------------------------
// Repack w[o][c][0..96] -> w3[c][seg][o] = bf16x4{ w[o][c][3seg .. 3seg+3] }
// 32*32*32 * 8B = 256 KB. o innermost: the main kernel's gather is fully
// coalesced (32 lanes x 8B = 256B contiguous per (c,seg)).
// ---------------------------------------------------------------------------
__global__ __launch_bounds__(256) void repack_w_kernel(const float* __restrict__ w,
                                                       uint2* __restrict__ w3) {
    int i = blockIdx.x * blockDim.x + threadIdx.x;   // 0 .. 32767
    if (i >= NC * SEGS * NO) return;
    int o   = i & 31;
    int seg = (i >> 5) & 31;
    int c   = i >> 10;
    const float* p = w + (o * NC + c) * WLEN + 3 * seg;
    unsigned b0 = f2bf(p[0]);
    unsigned b1 = f2bf(p[1]);
    unsigned b2 = f2bf(p[2]);
    unsigned b3 = f2bf(p[3]);
    w3[i] = make_uint2(b0 | (b1 << 16), b2 | (b3 << 16));
}

// ---------------------------------------------------------------------------
// Main kernel. Block = (b, tile of 8 nodes), 256 threads.
// Phase 1: 32c x 8m basis (fp32) + precomputed w3 element offset into LDS.
// Phase 2: thread = (o = tid&31, mt = tid>>5). Per c: LDS broadcast of
//          basis4/off (same addr for 32 o-lanes), coalesced 256B bf16 gather,
//          expand to fp32 (2 shifts + 2 ands), 4 FMA.
// ---------------------------------------------------------------------------
template <bool USE_W3>
__global__ __launch_bounds__(256) void pw_main_kernel(const float* __restrict__ x,
                                                      const float* __restrict__ w,
                                                      const uint2* __restrict__ w3,
                                                      float* __restrict__ out) {
    const int blk = blockIdx.x;          // 0 .. 2047
    const int b   = blk >> 7;            // 16 batches
    const int m0  = (blk & 127) * 8;     // node-tile base

    __shared__ float4 sb[NC][8];         // basis, 4 KB
    __shared__ int    soff[NC][8];       // (c*32+sg)*32 element offsets, 1 KB

    const int tid = threadIdx.x;

    // ---- phase 1: basis + weight-offset for this (b, m-tile)
    {
        const int c  = tid >> 3;
        const int mt = tid & 7;
        const float xv = x[(b * NC + c) * NM + m0 + mt];

        // id = clip(trunc((x+1)/2*32), 0, 31); (x+1)*16 is bit-exact equal.
        float v  = (xv + 1.0f) * 16.0f;
        int   id = (int)v;               // trunc-toward-zero == astype(int32)
        id = min(max(id, 0), SEGS - 1);

        // x_in = 32*(x - x_min) - 1, x_min = id/16 - 1 (exact)
        const float x_min = (float)id * 0.0625f - 1.0f;
        const float t     = (xv - x_min) * 32.0f - 1.0f;

        // Lagrange basis at Chebyshev points X = {-1, -0.5, 0.5, 1}
        const float d0 = t + 1.0f;
        const float d1 = t + 0.5f;
        const float d2 = t - 0.5f;
        const float d3 = t - 1.0f;
        float4 bb;
        bb.x = d1 * d2 * d3 * (-0.66666667f);  // denom -1.5
        bb.y = d0 * d2 * d3 * ( 1.33333333f);  // denom  0.75
        bb.z = d0 * d1 * d3 * (-1.33333333f);  // denom -0.75
        bb.w = d0 * d1 * d2 * ( 0.66666667f);  // denom  1.5

        sb[c][mt]   = bb;
        soff[c][mt] = (c * SEGS + id) * NO;    // element offset, add o in phase 2
    }
    __syncthreads();

    // ---- phase 2: one output per thread; o innermost across lanes
    const int o  = tid & 31;
    const int mt = tid >> 5;

    float acc = 0.0f;
#pragma unroll
    for (int c = 0; c < NC; ++c) {
        const float4 bb  = sb[c][mt];        // 32-lane same-address broadcast
        const int   base = soff[c][mt];
        float w0, w1, w2, w3v;
        if (USE_W3) {
            uint2 pw = w3[base + o];         // coalesced: 256B per 32 lanes
            w0  = __uint_as_float(pw.x << 16);
            w1  = __uint_as_float(pw.x & 0xffff0000u);
            w2  = __uint_as_float(pw.y << 16);
            w3v = __uint_as_float(pw.y & 0xffff0000u);
        } else {
            // fallback: direct fp32 gather from original layout
            const int sg = base / NO - ((base / NO) >> 5 << 5); // unused path
            const float* p = w + (o * NC + (base / (SEGS * NO))) * WLEN + 3 * sg;
            w0 = p[0]; w1 = p[1]; w2 = p[2]; w3v = p[3];
        }
        acc = fmaf(bb.x, w0, acc);
        acc = fmaf(bb.y, w1, acc);
        acc = fmaf(bb.z, w2, acc);
        acc = fmaf(bb.w, w3v, acc);
    }

    out[(b * NO + o) * NM + m0 + mt] = acc;
}

extern "C" void kernel_launch(void* const* d_in, const int* in_sizes, int n_in,
                              void* d_out, int out_size, void* d_ws, size_t ws_size,
                              hipStream_t stream) {
    const float* x = (const float*)d_in[0];   // (16, 32, 1024)
    const float* w = (const float*)d_in[1];   // (32, 32, 97)
    float* out = (float*)d_out;               // (16, 32, 1024)

    const size_t w3_bytes = (size_t)NC * SEGS * NO * sizeof(uint2);  // 256 KB

    if (ws_size >= w3_bytes) {
        uint2* w3 = (uint2*)d_ws;
        repack_w_kernel<<<(NC * SEGS * NO + 255) / 256, 256, 0, stream>>>(w, w3);
        pw_main_kernel<true><<<NB * (NM / 8), 256, 0, stream>>>(x, w, w3, out);
    } else {
        pw_main_kernel<false><<<NB * (NM / 8), 256, 0, stream>>>(x, w, nullptr, out);
    }
}

// Round 4
// 66.570 us; speedup vs baseline: 1.0214x; 1.0214x over previous
//
#include <hip/hip_runtime.h>

// Problem constants (match reference)
#define NB 16      // BATCH
#define NC 32      // IN_CH
#define NO 32      // OUT_CH
#define NM 1024    // NODES
#define SEGS 32
#define WLEN 97    // (N-1)*SEGMENTS + 1
#define MT 16      // m-nodes per block (phase-2 tile)

// ---------------------------------------------------------------------------
// Repack w[o][c][0..96] -> w3[c][seg][o] = float4{ w[o][c][3seg .. 3seg+3] }
// 32*32*32 float4 = 512 KB. o innermost: main kernel's gather is coalesced
// (16 lanes x 16B = 256B contiguous per (c,seg,o-half)).
// ---------------------------------------------------------------------------
__global__ __launch_bounds__(256) void repack_w_kernel(const float* __restrict__ w,
                                                       float4* __restrict__ w3) {
    int i = blockIdx.x * blockDim.x + threadIdx.x;   // 0 .. 32767
    if (i >= NC * SEGS * NO) return;
    int o   = i & 31;
    int seg = (i >> 5) & 31;
    int c   = i >> 10;
    const float* p = w + (o * NC + c) * WLEN + 3 * seg;
    w3[i] = make_float4(p[0], p[1], p[2], p[3]);
}

__device__ __forceinline__ float4 lagrange_basis(float xv, int& id_out) {
    // id = clip(trunc((x+1)/2*32), 0, 31); (x+1)*16 is bit-exact equal.
    float v  = (xv + 1.0f) * 16.0f;
    int   id = (int)v;                 // trunc-toward-zero == astype(int32)
    id = min(max(id, 0), SEGS - 1);
    // x_in = 32*(x - x_min) - 1, x_min = id/16 - 1 (exact)
    const float x_min = (float)id * 0.0625f - 1.0f;
    const float t     = (xv - x_min) * 32.0f - 1.0f;
    // Lagrange basis at Chebyshev points X = {-1, -0.5, 0.5, 1}
    const float d0 = t + 1.0f;
    const float d1 = t + 0.5f;
    const float d2 = t - 0.5f;
    const float d3 = t - 1.0f;
    float4 bb;
    bb.x = d1 * d2 * d3 * (-0.66666667f);  // denom -1.5
    bb.y = d0 * d2 * d3 * ( 1.33333333f);  // denom  0.75
    bb.z = d0 * d1 * d3 * (-1.33333333f);  // denom -0.75
    bb.w = d0 * d1 * d2 * ( 0.66666667f);  // denom  1.5
    id_out = id;
    return bb;
}

// ---------------------------------------------------------------------------
// Main kernel. Block = (b, tile of 16 nodes), 256 threads = 4 waves.
// Wave lane = (o_pair = lane&15 handling o_pair and o_pair+16, mt = wave*4 + lane>>4).
// Phase 1: 32c x 16m basis + w3 row offset into LDS (2 entries per thread).
// Phase 2: hoist this thread's 32 offsets to registers (8x ds_read_b128),
//          then fully-unrolled c-loop: 1 LDS b128 basis broadcast +
//          2 coalesced dwordx4 w-loads + 8 FMA for 2 outputs.
// ---------------------------------------------------------------------------
__global__ __launch_bounds__(256) void pw_main_kernel(const float* __restrict__ x,
                                                      const float4* __restrict__ w3,
                                                      float* __restrict__ out) {
    const int blk = blockIdx.x;          // 0 .. 1023
    const int b   = blk >> 6;            // 16 batches
    const int m0  = (blk & 63) * MT;     // node-tile base

    __shared__ float4 sb[NC][17];        // basis [c][mt], padded: write conflicts <=2-way
    __shared__ int    soff[MT][36];      // w3 row offsets [mt][c], row 144B (16B-aligned)

    const int tid = threadIdx.x;

    // ---- phase 1: basis + weight-row offset, 2 (c,mt) entries per thread
    {
        const int c   = tid >> 3;
        const int mtb = tid & 7;
#pragma unroll
        for (int k = 0; k < 2; ++k) {
            const int mt = mtb + 8 * k;
            const float xv = x[(b * NC + c) * NM + m0 + mt];
            int id;
            float4 bb = lagrange_basis(xv, id);
            sb[c][mt]   = bb;
            soff[mt][c] = (c * SEGS + id) * NO;   // float4-element offset of row
        }
    }
    __syncthreads();

    // ---- phase 2: 2 outputs per thread (o_pair, o_pair+16) at node mt
    const int lane = tid & 63;
    const int wid  = tid >> 6;
    const int op   = lane & 15;
    const int mt   = wid * 4 + (lane >> 4);

    // hoist all 32 row offsets into registers (breaks per-iter LDS dep chain)
    int4 offs[8];
    {
        const int4* sp = (const int4*)&soff[mt][0];
#pragma unroll
        for (int k = 0; k < 8; ++k) offs[k] = sp[k];
    }

    const float4* __restrict__ wp = w3 + op;

    float acc0 = 0.0f, acc1 = 0.0f;
#pragma unroll
    for (int k = 0; k < 8; ++k) {
        const int4 o4 = offs[k];
#pragma unroll
        for (int j = 0; j < 4; ++j) {
            const int c    = 4 * k + j;
            const int base = (j == 0) ? o4.x : (j == 1) ? o4.y : (j == 2) ? o4.z : o4.w;
            const float4 bb  = sb[c][mt];      // 16-lane same-address broadcast
            const float4 wv0 = wp[base];       // lanes 0..15: 256B contiguous
            const float4 wv1 = wp[base + 16];  // second o-half, 256B contiguous
            acc0 = fmaf(bb.x, wv0.x, acc0);
            acc0 = fmaf(bb.y, wv0.y, acc0);
            acc0 = fmaf(bb.z, wv0.z, acc0);
            acc0 = fmaf(bb.w, wv0.w, acc0);
            acc1 = fmaf(bb.x, wv1.x, acc1);
            acc1 = fmaf(bb.y, wv1.y, acc1);
            acc1 = fmaf(bb.z, wv1.z, acc1);
            acc1 = fmaf(bb.w, wv1.w, acc1);
        }
    }

    out[(b * NO + op) * NM + m0 + mt]        = acc0;
    out[(b * NO + op + 16) * NM + m0 + mt]   = acc1;
}

// ---------------------------------------------------------------------------
// Fallback (ws too small): one thread per output, direct gather from w.
// ---------------------------------------------------------------------------
__global__ __launch_bounds__(256) void pw_fallback_kernel(const float* __restrict__ x,
                                                          const float* __restrict__ w,
                                                          float* __restrict__ out) {
    const int blk = blockIdx.x;          // 0 .. 2047
    const int b   = blk >> 7;
    const int m   = (blk & 127) * 8 + (threadIdx.x & 7);
    const int o   = threadIdx.x >> 3;

    float acc = 0.0f;
    for (int c = 0; c < NC; ++c) {
        const float xv = x[(b * NC + c) * NM + m];
        int id;
        float4 bb = lagrange_basis(xv, id);
        const float* p = w + (o * NC + c) * WLEN + 3 * id;
        acc = fmaf(bb.x, p[0], acc);
        acc = fmaf(bb.y, p[1], acc);
        acc = fmaf(bb.z, p[2], acc);
        acc = fmaf(bb.w, p[3], acc);
    }
    out[(b * NO + o) * NM + m] = acc;
}

extern "C" void kernel_launch(void* const* d_in, const int* in_sizes, int n_in,
                              void* d_out, int out_size, void* d_ws, size_t ws_size,
                              hipStream_t stream) {
    const float* x = (const float*)d_in[0];   // (16, 32, 1024)
    const float* w = (const float*)d_in[1];   // (32, 32, 97)
    float* out = (float*)d_out;               // (16, 32, 1024)

    const size_t w3_bytes = (size_t)NC * SEGS * NO * sizeof(float4);  // 512 KB

    if (ws_size >= w3_bytes) {
        float4* w3 = (float4*)d_ws;
        repack_w_kernel<<<(NC * SEGS * NO + 255) / 256, 256, 0, stream>>>(w, w3);
        pw_main_kernel<<<NB * (NM / MT), 256, 0, stream>>>(x, w3, out);
    } else {
        pw_fallback_kernel<<<NB * (NM / 8), 256, 0, stream>>>(x, w, out);
    }
}